// Round 1
// 172.312 us; speedup vs baseline: 1.0887x; 1.0887x over previous
//
#include <hip/hip_runtime.h>
#include <cstdint>

// Fused butterfly-GLU-butterfly, round 4: move the butterflies onto the matrix
// cores. 5-stage butterfly groups = block-diagonal 32x32 dense matrices.
// Pre-pass builds 384 combined 32x32 bf16 matrices (stage-10 twiddles folded
// into L2B row scalings) in d_ws, stored in mfma_f32_16x16x32_bf16 A-fragment
// order. Main kernel: 32 rows/block, 512 thr (8 waves), 6 MFMA phases per half.
// LDS: two 64KB bf16 activation tiles ([32 rows][1024], XOR-swizzled
// byte^=(row&7)<<4) + 16KB transposed b1. x loaded once into register B-frags;
// half-0 L2B result kept in regs (bf16-packed) until the final z0+z1+b2.

typedef float          v4f __attribute__((ext_vector_type(4)));
typedef unsigned int   u4i __attribute__((ext_vector_type(4)));
typedef unsigned int   u2i __attribute__((ext_vector_type(2)));
typedef short          bf8 __attribute__((ext_vector_type(8)));  // 8 x bf16

#define MFMA16(A, B, C) __builtin_amdgcn_mfma_f32_16x16x32_bf16(A, B, C, 0, 0, 0)

// pack two fp32 -> bf16x2 (a -> low16, b -> high16), round-to-nearest-ish
__device__ __forceinline__ unsigned pk2(float a, float b) {
    unsigned ua = __float_as_uint(a) + 0x8000u;
    unsigned ub = __float_as_uint(b) + 0x8000u;
    return __builtin_amdgcn_perm(ub, ua, 0x07060302u);
}

__device__ __forceinline__ float sigmf(float g) {
    return __builtin_amdgcn_rcpf(1.0f + __expf(-g));
}
__device__ __forceinline__ v4f sig4(v4f g) {
    v4f r; r.x = sigmf(g.x); r.y = sigmf(g.y); r.z = sigmf(g.z); r.w = sigmf(g.w);
    return r;
}

// byte offset into a [32 rows][1024 halfword] bf16 LDS tile, bank-swizzled
__device__ __forceinline__ int ab(int row, int hw) {
    return (row << 11) + (((hw) << 1) ^ ((row & 7) << 4));
}

// ---------------------------------------------------------------------------
// Pre-pass: build the 384 combined 32x32 matrices into d_ws (bf16, frag order)
//   mid   0..127 : L1A  [s][g]  stages 0..4 , p = 32g + r        (tw1)
//   mid 128..255 : L1B  [s][l]  stages 5..9 , p = l + 32r        (tw1)
//   mid 256..319 : L2A  [g2]    stages 0..4 , p = 32g2 + r       (tw2)
//   mid 320..383 : L2B  [b][l2] stages 5..9 , p = l2+32r+1024b   (tw2),
//                  rows scaled by tw2[stage10][l2+32r][0][b]
// Element M[r][c] lives at ws16[((mid*2 + (r>>4))*64 + (r&15) + 16*(c>>3))*8 + (c&7)]
// i.e. A-frag: lane holds A[row = lane&15][k = 8*(lane>>4)+j], j contiguous.
// ---------------------------------------------------------------------------
__global__ void build_mats(const float* __restrict__ tw1,
                           const float* __restrict__ tw2,
                           unsigned short* __restrict__ wsm)
{
    const int mid = blockIdx.x * 2 + (threadIdx.x >> 5);
    const int c   = threadIdx.x & 31;

    const float* twf; int np, rbase, rstep, j0, scaleb = -1, l2s = 0;
    if (mid < 128)      { twf = tw1 + (mid >> 5) * 20480;        np = 512;  rbase = (mid & 31) * 32; rstep = 1;  j0 = 0; }
    else if (mid < 256) { twf = tw1 + ((mid - 128) >> 5) * 20480; np = 512; rbase = mid & 31;        rstep = 32; j0 = 5; }
    else if (mid < 320) { twf = tw2; np = 1024; rbase = (mid - 256) * 32; rstep = 1; j0 = 0; }
    else                { twf = tw2; np = 1024; l2s = mid & 31; scaleb = (mid - 320) >> 5;
                          rbase = l2s + (scaleb << 10); rstep = 32; j0 = 5; }

    float v[32];
    #pragma unroll
    for (int r = 0; r < 32; ++r) v[r] = (r == c) ? 1.0f : 0.0f;

    #pragma unroll
    for (int jj = 0; jj < 5; ++jj) {
        const int j = j0 + jj;
        #pragma unroll
        for (int pr = 0; pr < 16; ++pr) {
            const int r0   = ((pr >> jj) << (jj + 1)) | (pr & ((1 << jj) - 1));
            const int r1   = r0 | (1 << jj);
            const int p0   = rbase + r0 * rstep;
            const int tidx = ((p0 >> (j + 1)) << j) | (p0 & ((1 << j) - 1));
            const v4f T    = *(const v4f*)(twf + (size_t)(j * np + tidx) * 4);
            const float a = v[r0], b = v[r1];
            v[r0] = T.x * a + T.y * b;
            v[r1] = T.z * a + T.w * b;
        }
    }
    if (scaleb >= 0) {
        #pragma unroll
        for (int r = 0; r < 32; ++r)
            v[r] *= tw2[(size_t)(10 * 1024 + l2s + 32 * r) * 4 + scaleb];
    }
    #pragma unroll
    for (int r = 0; r < 32; ++r) {
        const int mt   = r >> 4;
        const int lane = (r & 15) + ((c >> 3) << 4);
        wsm[((size_t)(mid * 2 + mt) * 64 + lane) * 8 + (c & 7)] =
            (unsigned short)((__float_as_uint(v[r]) + 0x8000u) >> 16);
    }
}

// ---------------------------------------------------------------------------
// Main fused kernel. 512 blocks x 32 rows. LDS = actA(64K) + actB(64K) + b1t(16K).
// Transposed-tile convention: value at position p stored at hw = 32*(p&31)+(p>>5),
// so an A-phase (writes pack across its 4 groups) and the next B-phase
// (b128 fragment reads) are both contiguous.
// ---------------------------------------------------------------------------
__global__ __launch_bounds__(512) void glu_bfly(
    const float* __restrict__ x, const float* __restrict__ b1,
    const float* __restrict__ b2, const bf8* __restrict__ mats,
    float* __restrict__ out)
{
    extern __shared__ char lds[];
    char*  actA = lds;
    char*  actB = lds + 65536;
    float* b1t  = (float*)(lds + 131072);

    const int t = threadIdx.x, w = t >> 6, l = t & 63, lr = l & 15, lk = l >> 4;
    const int row0 = blockIdx.x * 32;
    const v4f vz = {0.f, 0.f, 0.f, 0.f};

    // ---- stage b1 -> b1t[s][l][m] = b1[s*1024 + l + 32m] (fragment-friendly) ----
    {
        const v4f* bp = (const v4f*)(b1 + t * 8);
        const v4f a = bp[0], b = bp[1];
        const float vals[8] = {a.x, a.y, a.z, a.w, b.x, b.y, b.z, b.w};
        #pragma unroll
        for (int k = 0; k < 8; ++k) {
            const int gid = t * 8 + k, s = gid >> 10, r = gid & 1023;
            b1t[(s << 10) + ((r & 31) << 5) + (r >> 5)] = vals[k];
        }
    }

    // ---- x B-fragments, loaded once, reused by all four L1A passes ----
    bf8 xf[4][2];
    #pragma unroll
    for (int gi = 0; gi < 4; ++gi)
    #pragma unroll
    for (int nh = 0; nh < 2; ++nh) {
        const float* xp = x + (size_t)(row0 + nh * 16 + lr) * 1024 + (w * 4 + gi) * 32 + lk * 8;
        const v4f a = *(const v4f*)xp;
        const v4f b = *(const v4f*)(xp + 4);
        u4i uu; uu.x = pk2(a.x, a.y); uu.y = pk2(a.z, a.w);
        uu.z = pk2(b.x, b.y); uu.w = pk2(b.z, b.w);
        xf[gi][nh] = __builtin_bit_cast(bf8, uu);
    }
    __syncthreads();

    unsigned z0p[4][2][2][2];   // half-0 L2B result, bf16-packed
    v4f fin[4][2][2];           // z0 + z1 (pre-bias)

    #pragma unroll
    for (int h = 0; h < 2; ++h) {
        const int sa = h, sg = h + 2;

        // ---- L1A for stack sa -> actA, then stack sg -> actB (transposed) ----
        #pragma unroll
        for (int pass = 0; pass < 2; ++pass) {
            const int s = (pass == 0) ? sa : sg;
            char* dst = (pass == 0) ? actA : actB;
            v4f acc[4][2][2];
            #pragma unroll
            for (int gi = 0; gi < 4; ++gi) {
                const int mid = s * 32 + w * 4 + gi;
                const bf8 a0 = mats[(mid * 2 + 0) * 64 + l];
                const bf8 a1 = mats[(mid * 2 + 1) * 64 + l];
                #pragma unroll
                for (int nh = 0; nh < 2; ++nh) {
                    acc[gi][nh][0] = MFMA16(a0, xf[gi][nh], vz);
                    acc[gi][nh][1] = MFMA16(a1, xf[gi][nh], vz);
                }
            }
            #pragma unroll
            for (int nh = 0; nh < 2; ++nh)
            #pragma unroll
            for (int mt = 0; mt < 2; ++mt)
            #pragma unroll
            for (int rg = 0; rg < 4; ++rg) {
                const int m = mt * 16 + lk * 4 + rg;
                u2i pv;
                pv.x = pk2(acc[0][nh][mt][rg], acc[1][nh][mt][rg]);
                pv.y = pk2(acc[2][nh][mt][rg], acc[3][nh][mt][rg]);
                *(u2i*)(dst + ab(nh * 16 + lr, 32 * m + 4 * w)) = pv;
            }
            __syncthreads();
        }

        // ---- L1B(a) + L1B(g) + bias + GLU -> u (plain) into actA ----
        {
            v4f uacc[4][2][2];
            #pragma unroll
            for (int li = 0; li < 4; ++li) {
                const int lg = w * 4 + li;
                v4f ha[2][2], hg[2][2];
                {
                    const int mid = 128 + sa * 32 + lg;
                    const bf8 a0 = mats[(mid * 2 + 0) * 64 + l];
                    const bf8 a1 = mats[(mid * 2 + 1) * 64 + l];
                    const bf8 f0 = *(const bf8*)(actA + ab(lr,      32 * lg + 8 * lk));
                    const bf8 f1 = *(const bf8*)(actA + ab(16 + lr, 32 * lg + 8 * lk));
                    ha[0][0] = MFMA16(a0, f0, vz); ha[0][1] = MFMA16(a1, f0, vz);
                    ha[1][0] = MFMA16(a0, f1, vz); ha[1][1] = MFMA16(a1, f1, vz);
                }
                {
                    const int mid = 128 + sg * 32 + lg;
                    const bf8 a0 = mats[(mid * 2 + 0) * 64 + l];
                    const bf8 a1 = mats[(mid * 2 + 1) * 64 + l];
                    const bf8 f0 = *(const bf8*)(actB + ab(lr,      32 * lg + 8 * lk));
                    const bf8 f1 = *(const bf8*)(actB + ab(16 + lr, 32 * lg + 8 * lk));
                    hg[0][0] = MFMA16(a0, f0, vz); hg[0][1] = MFMA16(a1, f0, vz);
                    hg[1][0] = MFMA16(a0, f1, vz); hg[1][1] = MFMA16(a1, f1, vz);
                }
                #pragma unroll
                for (int mt = 0; mt < 2; ++mt) {
                    const v4f ba = *(const v4f*)&b1t[((sa * 32 + lg) << 5) + mt * 16 + lk * 4];
                    const v4f bg = *(const v4f*)&b1t[((sg * 32 + lg) << 5) + mt * 16 + lk * 4];
                    #pragma unroll
                    for (int nh = 0; nh < 2; ++nh)
                        uacc[li][nh][mt] = (ha[nh][mt] + ba) * sig4(hg[nh][mt] + bg);
                }
            }
            __syncthreads();   // all reads of actA/actB complete
            #pragma unroll
            for (int nh = 0; nh < 2; ++nh)
            #pragma unroll
            for (int mt = 0; mt < 2; ++mt)
            #pragma unroll
            for (int rg = 0; rg < 4; ++rg) {
                const int m = mt * 16 + lk * 4 + rg;
                u2i pv;
                pv.x = pk2(uacc[0][nh][mt][rg], uacc[1][nh][mt][rg]);
                pv.y = pk2(uacc[2][nh][mt][rg], uacc[3][nh][mt][rg]);
                *(u2i*)(actA + ab(nh * 16 + lr, 32 * m + 4 * w)) = pv;  // plain: hw = p
            }
            __syncthreads();
        }

        // ---- L2A: u (actA, plain) -> zA (actB, transposed) ----
        {
            v4f acc[4][2][2];
            #pragma unroll
            for (int gi = 0; gi < 4; ++gi) {
                const int g = w * 4 + gi, mid = 256 + 32 * h + g;
                const bf8 a0 = mats[(mid * 2 + 0) * 64 + l];
                const bf8 a1 = mats[(mid * 2 + 1) * 64 + l];
                #pragma unroll
                for (int nh = 0; nh < 2; ++nh) {
                    const bf8 f = *(const bf8*)(actA + ab(nh * 16 + lr, 32 * g + 8 * lk));
                    acc[gi][nh][0] = MFMA16(a0, f, vz);
                    acc[gi][nh][1] = MFMA16(a1, f, vz);
                }
            }
            #pragma unroll
            for (int nh = 0; nh < 2; ++nh)
            #pragma unroll
            for (int mt = 0; mt < 2; ++mt)
            #pragma unroll
            for (int rg = 0; rg < 4; ++rg) {
                const int m = mt * 16 + lk * 4 + rg;
                u2i pv;
                pv.x = pk2(acc[0][nh][mt][rg], acc[1][nh][mt][rg]);
                pv.y = pk2(acc[2][nh][mt][rg], acc[3][nh][mt][rg]);
                *(u2i*)(actB + ab(nh * 16 + lr, 32 * m + 4 * w)) = pv;
            }
            __syncthreads();
        }

        // ---- L2B (stage-10 twiddles pre-folded): result stays in registers ----
        #pragma unroll
        for (int li = 0; li < 4; ++li) {
            const int lg = w * 4 + li, mid = 320 + 32 * h + lg;
            const bf8 a0 = mats[(mid * 2 + 0) * 64 + l];
            const bf8 a1 = mats[(mid * 2 + 1) * 64 + l];
            const bf8 f0 = *(const bf8*)(actB + ab(lr,      32 * lg + 8 * lk));
            const bf8 f1 = *(const bf8*)(actB + ab(16 + lr, 32 * lg + 8 * lk));
            v4f zz[2][2];
            zz[0][0] = MFMA16(a0, f0, vz); zz[0][1] = MFMA16(a1, f0, vz);
            zz[1][0] = MFMA16(a0, f1, vz); zz[1][1] = MFMA16(a1, f1, vz);
            if (h == 0) {
                #pragma unroll
                for (int nh = 0; nh < 2; ++nh)
                #pragma unroll
                for (int mt = 0; mt < 2; ++mt) {
                    z0p[li][nh][mt][0] = pk2(zz[nh][mt].x, zz[nh][mt].y);
                    z0p[li][nh][mt][1] = pk2(zz[nh][mt].z, zz[nh][mt].w);
                }
            } else {
                #pragma unroll
                for (int nh = 0; nh < 2; ++nh)
                #pragma unroll
                for (int mt = 0; mt < 2; ++mt) {
                    v4f uz;
                    uz.x = __uint_as_float(z0p[li][nh][mt][0] << 16);
                    uz.y = __uint_as_float(z0p[li][nh][mt][0] & 0xffff0000u);
                    uz.z = __uint_as_float(z0p[li][nh][mt][1] << 16);
                    uz.w = __uint_as_float(z0p[li][nh][mt][1] & 0xffff0000u);
                    fin[li][nh][mt] = zz[nh][mt] + uz;
                }
            }
        }
    } // halves

    // ---- epilogue: stage fin through LDS (fp32) for coalesced out = z0+z1+b2 ----
    #pragma unroll
    for (int nh = 0; nh < 2; ++nh) {
        #pragma unroll
        for (int mt = 0; mt < 2; ++mt)
        #pragma unroll
        for (int rg = 0; rg < 4; ++rg) {
            const int p0 = 4 * w + 32 * (mt * 16 + lk * 4 + rg);
            v4f vv;
            vv.x = fin[0][nh][mt][rg]; vv.y = fin[1][nh][mt][rg];
            vv.z = fin[2][nh][mt][rg]; vv.w = fin[3][nh][mt][rg];
            *(v4f*)(actA + (lr << 12) + ((p0 << 2) ^ ((lr & 7) << 4))) = vv;
        }
        __syncthreads();
        {
            const int row = t >> 5, c0 = (t & 31) * 4;
            #pragma unroll
            for (int i = 0; i < 8; ++i) {
                const int col = c0 + 128 * i;
                v4f ov = *(const v4f*)(actA + (row << 12) + ((col << 2) ^ ((row & 7) << 4)));
                ov += *(const v4f*)(b2 + col);
                *(v4f*)(out + (size_t)(row0 + nh * 16 + row) * 1024 + col) = ov;
            }
        }
        __syncthreads();
    }
}

extern "C" void kernel_launch(void* const* d_in, const int* in_sizes, int n_in,
                              void* d_out, int out_size, void* d_ws, size_t ws_size,
                              hipStream_t stream) {
    const float* x   = (const float*)d_in[0];
    const float* tw1 = (const float*)d_in[1];
    const float* b1  = (const float*)d_in[2];
    const float* tw2 = (const float*)d_in[3];
    const float* b2  = (const float*)d_in[4];

    // 384 combined matrices, 2 per 64-thread block -> 768 KB of d_ws
    build_mats<<<192, 64, 0, stream>>>(tw1, tw2, (unsigned short*)d_ws);

    (void)hipFuncSetAttribute((const void*)glu_bfly,
                              hipFuncAttributeMaxDynamicSharedMemorySize, 147456);
    glu_bfly<<<512, 512, 147456, stream>>>(x, b1, b2, (const bf8*)d_ws,
                                           (float*)d_out);
}

// Round 2
// 158.575 us; speedup vs baseline: 1.1830x; 1.0866x over previous
//
#include <hip/hip_runtime.h>
#include <cstdint>

// Fused butterfly-GLU-butterfly, round 5.
// Round-4 post-mortem: MfmaUtil 6.9 / VALUBusy 22.6 / Occupancy 20.7 -> the
// 144KB-LDS block caps the CU at 1 block (8 waves); ~16 barrier phases fully
// serialize. Fix A: 16-row blocks (grid 1024), actA/actB 32KB + b1 staged bf16
// (8KB) = 72KB LDS -> 2 blocks/CU (16 waves). Per-element math is identical to
// the verified round-4 kernel (nh dimension removed). Fix B: build_mats was
// ~26us (192 tiny blocks, 80 scattered dependent twiddle loads/thread):
// cooperative LDS prefetch of twiddles, same chain. Fix C: s_setprio(1) around
// MFMA clusters (pays once 2 blocks co-reside).

typedef float          v4f __attribute__((ext_vector_type(4)));
typedef unsigned int   u4i __attribute__((ext_vector_type(4)));
typedef unsigned int   u2i __attribute__((ext_vector_type(2)));
typedef short          bf8 __attribute__((ext_vector_type(8)));  // 8 x bf16

#define MFMA16(A, B, C) __builtin_amdgcn_mfma_f32_16x16x32_bf16(A, B, C, 0, 0, 0)

__device__ __forceinline__ unsigned pk2(float a, float b) {
    unsigned ua = __float_as_uint(a) + 0x8000u;
    unsigned ub = __float_as_uint(b) + 0x8000u;
    return __builtin_amdgcn_perm(ub, ua, 0x07060302u);  // {b.hi16, a.hi16}
}

__device__ __forceinline__ v4f ub4(u2i u) {   // unpack 4 bf16 -> v4f
    v4f r;
    r.x = __uint_as_float(u.x << 16); r.y = __uint_as_float(u.x & 0xffff0000u);
    r.z = __uint_as_float(u.y << 16); r.w = __uint_as_float(u.y & 0xffff0000u);
    return r;
}

__device__ __forceinline__ float sigmf(float g) {
    return __builtin_amdgcn_rcpf(1.0f + __expf(-g));
}
__device__ __forceinline__ v4f sig4(v4f g) {
    v4f r; r.x = sigmf(g.x); r.y = sigmf(g.y); r.z = sigmf(g.z); r.w = sigmf(g.w);
    return r;
}

// byte offset into a [16 rows][1024 halfword] bf16 LDS tile, bank-swizzled
__device__ __forceinline__ int ab16(int row, int hw) {
    return (row << 11) + (((hw) << 1) ^ ((row & 7) << 4));
}

// ---------------------------------------------------------------------------
// Pre-pass: 384 combined 32x32 bf16 matrices into d_ws (A-fragment order).
//   mid   0..127 : L1A [s][g]  stages 0..4 , p = 32g + r        (tw1)
//   mid 128..255 : L1B [s][l]  stages 5..9 , p = l + 32r        (tw1)
//   mid 256..319 : L2A [g2]    stages 0..4 , p = 32g2 + r       (tw2)
//   mid 320..383 : L2B [b][l2] stages 5..9 , p = l2+32r+1024b   (tw2),
//                  rows scaled by tw2[stage10][l2+32r][0][b]
// v2: cooperative LDS prefetch of the 160 twiddle v4f + 64 scale scalars,
// then the (verified) per-column chain runs out of LDS.
// ---------------------------------------------------------------------------
struct MP { const float* twf; int np, rbase, rstep, j0; };
__device__ __forceinline__ MP mparams(int mid, const float* tw1, const float* tw2) {
    MP p;
    if (mid < 128)      { p.twf = tw1 + (mid >> 5) * 20480;         p.np = 512;  p.rbase = (mid & 31) * 32; p.rstep = 1;  p.j0 = 0; }
    else if (mid < 256) { p.twf = tw1 + ((mid - 128) >> 5) * 20480; p.np = 512;  p.rbase = mid & 31;        p.rstep = 32; p.j0 = 5; }
    else if (mid < 320) { p.twf = tw2; p.np = 1024; p.rbase = (mid - 256) * 32; p.rstep = 1;  p.j0 = 0; }
    else                { p.twf = tw2; p.np = 1024;
                          p.rbase = (mid & 31) + (((mid - 320) >> 5) << 10);    p.rstep = 32; p.j0 = 5; }
    return p;
}

__global__ void build_mats(const float* __restrict__ tw1,
                           const float* __restrict__ tw2,
                           unsigned short* __restrict__ wsm)
{
    __shared__ v4f   tlds[160];   // 2 mids x 5 stages x 16 pairs
    __shared__ float slds[64];    // 2 mids x 32 stage-10 row scales
    const int t = threadIdx.x;
    const int midb = blockIdx.x * 2;

    #pragma unroll
    for (int qq = 0; qq < 3; ++qq) {
        const int q = t + qq * 64;
        if (q < 160) {
            const int ml = (q >= 80) ? 1 : 0, rem = q - ml * 80;
            const int jj = rem >> 4, pr = rem & 15;
            const MP p = mparams(midb + ml, tw1, tw2);
            const int j  = p.j0 + jj;
            const int r0 = ((pr >> jj) << (jj + 1)) | (pr & ((1 << jj) - 1));
            const int pp = p.rbase + r0 * p.rstep;
            const int tidx = ((pp >> (j + 1)) << j) | (pp & ((1 << j) - 1));
            tlds[q] = *(const v4f*)(p.twf + (size_t)(j * p.np + tidx) * 4);
        }
    }
    {
        const int ml = t >> 5, r = t & 31, mid = midb + ml;
        if (mid >= 320) {
            const int l2s = mid & 31, sb = (mid - 320) >> 5;
            slds[t] = tw2[(size_t)(10 * 1024 + l2s + 32 * r) * 4 + sb];
        }
    }
    __syncthreads();

    const int ml = t >> 5, c = t & 31, mid = midb + ml;
    float v[32];
    #pragma unroll
    for (int r = 0; r < 32; ++r) v[r] = (r == c) ? 1.0f : 0.0f;

    #pragma unroll
    for (int jj = 0; jj < 5; ++jj) {
        #pragma unroll
        for (int pr = 0; pr < 16; ++pr) {
            const int r0 = ((pr >> jj) << (jj + 1)) | (pr & ((1 << jj) - 1));
            const int r1 = r0 | (1 << jj);
            const v4f T  = tlds[ml * 80 + jj * 16 + pr];
            const float a = v[r0], b = v[r1];
            v[r0] = T.x * a + T.y * b;
            v[r1] = T.z * a + T.w * b;
        }
    }
    if (mid >= 320) {
        #pragma unroll
        for (int r = 0; r < 32; ++r) v[r] *= slds[ml * 32 + r];
    }
    #pragma unroll
    for (int r = 0; r < 32; ++r) {
        const int mt   = r >> 4;
        const int lane = (r & 15) + ((c >> 3) << 4);
        wsm[((size_t)(mid * 2 + mt) * 64 + lane) * 8 + (c & 7)] =
            (unsigned short)((__float_as_uint(v[r]) + 0x8000u) >> 16);
    }
}

// ---------------------------------------------------------------------------
// Main fused kernel. 1024 blocks x 16 rows x 512 thr.
// LDS 72KB = actA(32K) + actB(32K) + b1t16(8K bf16) -> 2 blocks/CU.
// Transposed-tile convention: value at position p stored at hw = 32*(p&31)+(p>>5).
// ---------------------------------------------------------------------------
__global__ __launch_bounds__(512, 4) void glu_bfly(
    const float* __restrict__ x, const float* __restrict__ b1,
    const float* __restrict__ b2, const bf8* __restrict__ mats,
    float* __restrict__ out)
{
    extern __shared__ char lds[];                 // 73728 B
    char*           actA  = lds;
    char*           actB  = lds + 32768;
    unsigned short* b1t16 = (unsigned short*)(lds + 65536);

    const int t = threadIdx.x, w = t >> 6, l = t & 63, lr = l & 15, lk = l >> 4;
    const int row0 = blockIdx.x * 16;
    const v4f vz = {0.f, 0.f, 0.f, 0.f};

    // ---- stage b1 (bf16) -> b1t16[(s<<10)+((r&31)<<5)+(r>>5)] -------------------
    {
        const v4f* bp = (const v4f*)(b1 + t * 8);
        const v4f a = bp[0], b = bp[1];
        const float vals[8] = {a.x, a.y, a.z, a.w, b.x, b.y, b.z, b.w};
        #pragma unroll
        for (int k = 0; k < 8; ++k) {
            const int gid = t * 8 + k, s = gid >> 10, r = gid & 1023;
            b1t16[(s << 10) + ((r & 31) << 5) + (r >> 5)] =
                (unsigned short)((__float_as_uint(vals[k]) + 0x8000u) >> 16);
        }
    }

    // ---- x B-fragments, loaded once, reused by all four L1A passes --------------
    bf8 xf[4];
    #pragma unroll
    for (int gi = 0; gi < 4; ++gi) {
        const float* xp = x + (size_t)(row0 + lr) * 1024 + (w * 4 + gi) * 32 + lk * 8;
        const v4f a = *(const v4f*)xp, b = *(const v4f*)(xp + 4);
        u4i uu; uu.x = pk2(a.x, a.y); uu.y = pk2(a.z, a.w);
        uu.z = pk2(b.x, b.y); uu.w = pk2(b.z, b.w);
        xf[gi] = __builtin_bit_cast(bf8, uu);
    }

    unsigned z0p[4][2][2];   // half-0 L2B result, bf16-packed
    v4f fin[4][2];           // z0 + z1 (pre-bias)

    #pragma unroll
    for (int h = 0; h < 2; ++h) {
        const int sa = h, sg = h + 2;

        // ---- L1A: stack sa -> actA, stack sg -> actB (transposed) ----
        #pragma unroll
        for (int pass = 0; pass < 2; ++pass) {
            const int s = pass ? sg : sa;
            char* dst = pass ? actB : actA;
            v4f acc[2][4];
            __builtin_amdgcn_s_setprio(1);
            #pragma unroll
            for (int mt = 0; mt < 2; ++mt)
            #pragma unroll
            for (int gi = 0; gi < 4; ++gi) {
                const bf8 am = mats[((s * 32 + w * 4 + gi) * 2 + mt) * 64 + l];
                acc[mt][gi] = MFMA16(am, xf[gi], vz);
            }
            __builtin_amdgcn_s_setprio(0);
            #pragma unroll
            for (int mt = 0; mt < 2; ++mt)
            #pragma unroll
            for (int rg = 0; rg < 4; ++rg) {
                const int m = mt * 16 + lk * 4 + rg;
                u2i pv;
                pv.x = pk2(acc[mt][0][rg], acc[mt][1][rg]);
                pv.y = pk2(acc[mt][2][rg], acc[mt][3][rg]);
                *(u2i*)(dst + ab16(lr, 32 * m + 4 * w)) = pv;
            }
            __syncthreads();
        }

        // ---- L1B(a) + L1B(g) + bias + GLU -> u (plain) into actA ----
        {
            v4f uacc[4][2];
            #pragma unroll
            for (int li = 0; li < 4; ++li) {
                const int lg = w * 4 + li;
                const bf8 fa = *(const bf8*)(actA + ab16(lr, 32 * lg + 8 * lk));
                const bf8 fg = *(const bf8*)(actB + ab16(lr, 32 * lg + 8 * lk));
                const int mida = 128 + sa * 32 + lg, midg = 128 + sg * 32 + lg;
                const bf8 aa0 = mats[(mida * 2 + 0) * 64 + l];
                const bf8 aa1 = mats[(mida * 2 + 1) * 64 + l];
                const bf8 ag0 = mats[(midg * 2 + 0) * 64 + l];
                const bf8 ag1 = mats[(midg * 2 + 1) * 64 + l];
                __builtin_amdgcn_s_setprio(1);
                const v4f ha0 = MFMA16(aa0, fa, vz), ha1 = MFMA16(aa1, fa, vz);
                const v4f hg0 = MFMA16(ag0, fg, vz), hg1 = MFMA16(ag1, fg, vz);
                __builtin_amdgcn_s_setprio(0);
                const int bia = ((sa * 32 + lg) << 5) + lk * 4;
                const int big = ((sg * 32 + lg) << 5) + lk * 4;
                const v4f ba0 = ub4(*(const u2i*)&b1t16[bia]);
                const v4f ba1 = ub4(*(const u2i*)&b1t16[bia + 16]);
                const v4f bg0 = ub4(*(const u2i*)&b1t16[big]);
                const v4f bg1 = ub4(*(const u2i*)&b1t16[big + 16]);
                uacc[li][0] = (ha0 + ba0) * sig4(hg0 + bg0);
                uacc[li][1] = (ha1 + ba1) * sig4(hg1 + bg1);
            }
            __syncthreads();   // all reads of actA/actB complete
            #pragma unroll
            for (int mt = 0; mt < 2; ++mt)
            #pragma unroll
            for (int rg = 0; rg < 4; ++rg) {
                const int m = mt * 16 + lk * 4 + rg;
                u2i pv;
                pv.x = pk2(uacc[0][mt][rg], uacc[1][mt][rg]);
                pv.y = pk2(uacc[2][mt][rg], uacc[3][mt][rg]);
                *(u2i*)(actA + ab16(lr, 32 * m + 4 * w)) = pv;  // plain: hw = p
            }
            __syncthreads();
        }

        // ---- L2A: u (actA, plain) -> zA (actB, transposed) ----
        {
            v4f acc[2][4];
            #pragma unroll
            for (int gi = 0; gi < 4; ++gi) {
                const int g = w * 4 + gi, mid = 256 + 32 * h + g;
                const bf8 f  = *(const bf8*)(actA + ab16(lr, 32 * g + 8 * lk));
                const bf8 a0 = mats[(mid * 2 + 0) * 64 + l];
                const bf8 a1 = mats[(mid * 2 + 1) * 64 + l];
                __builtin_amdgcn_s_setprio(1);
                acc[0][gi] = MFMA16(a0, f, vz);
                acc[1][gi] = MFMA16(a1, f, vz);
                __builtin_amdgcn_s_setprio(0);
            }
            #pragma unroll
            for (int mt = 0; mt < 2; ++mt)
            #pragma unroll
            for (int rg = 0; rg < 4; ++rg) {
                const int m = mt * 16 + lk * 4 + rg;
                u2i pv;
                pv.x = pk2(acc[mt][0][rg], acc[mt][1][rg]);
                pv.y = pk2(acc[mt][2][rg], acc[mt][3][rg]);
                *(u2i*)(actB + ab16(lr, 32 * m + 4 * w)) = pv;
            }
            __syncthreads();
        }

        // ---- L2B (stage-10 twiddles pre-folded): result stays in registers ----
        #pragma unroll
        for (int li = 0; li < 4; ++li) {
            const int lg = w * 4 + li, mid = 320 + 32 * h + lg;
            const bf8 f  = *(const bf8*)(actB + ab16(lr, 32 * lg + 8 * lk));
            const bf8 a0 = mats[(mid * 2 + 0) * 64 + l];
            const bf8 a1 = mats[(mid * 2 + 1) * 64 + l];
            __builtin_amdgcn_s_setprio(1);
            const v4f z0 = MFMA16(a0, f, vz);
            const v4f z1 = MFMA16(a1, f, vz);
            __builtin_amdgcn_s_setprio(0);
            if (h == 0) {
                z0p[li][0][0] = pk2(z0.x, z0.y); z0p[li][0][1] = pk2(z0.z, z0.w);
                z0p[li][1][0] = pk2(z1.x, z1.y); z0p[li][1][1] = pk2(z1.z, z1.w);
            } else {
                u2i u0; u0.x = z0p[li][0][0]; u0.y = z0p[li][0][1];
                u2i u1; u1.x = z0p[li][1][0]; u1.y = z0p[li][1][1];
                fin[li][0] = z0 + ub4(u0);
                fin[li][1] = z1 + ub4(u1);
            }
        }
    } // halves

    // ---- epilogue: stage fin (fp32) through lds[0,64K) for coalesced store ------
    __syncthreads();   // all actB reads of L2B(h=1) complete
    #pragma unroll
    for (int mt = 0; mt < 2; ++mt)
    #pragma unroll
    for (int rg = 0; rg < 4; ++rg) {
        const int p0 = 4 * w + 32 * (mt * 16 + lk * 4 + rg);
        v4f vv;
        vv.x = fin[0][mt][rg]; vv.y = fin[1][mt][rg];
        vv.z = fin[2][mt][rg]; vv.w = fin[3][mt][rg];
        *(v4f*)(lds + (lr << 12) + ((p0 << 2) ^ ((lr & 7) << 4))) = vv;
    }
    __syncthreads();
    {
        const int row = t >> 5, c0 = (t & 31) * 4;
        #pragma unroll
        for (int i = 0; i < 8; ++i) {
            const int col = c0 + 128 * i;
            v4f ov = *(const v4f*)(lds + (row << 12) + ((col << 2) ^ ((row & 7) << 4)));
            ov += *(const v4f*)(b2 + col);
            *(v4f*)(out + (size_t)(row0 + row) * 1024 + col) = ov;
        }
    }
}

extern "C" void kernel_launch(void* const* d_in, const int* in_sizes, int n_in,
                              void* d_out, int out_size, void* d_ws, size_t ws_size,
                              hipStream_t stream) {
    const float* x   = (const float*)d_in[0];
    const float* tw1 = (const float*)d_in[1];
    const float* b1  = (const float*)d_in[2];
    const float* tw2 = (const float*)d_in[3];
    const float* b2  = (const float*)d_in[4];

    build_mats<<<192, 64, 0, stream>>>(tw1, tw2, (unsigned short*)d_ws);

    (void)hipFuncSetAttribute((const void*)glu_bfly,
                              hipFuncAttributeMaxDynamicSharedMemorySize, 73728);
    glu_bfly<<<1024, 512, 73728, stream>>>(x, b1, b2, (const bf8*)d_ws,
                                           (float*)d_out);
}

// Round 3
// 154.452 us; speedup vs baseline: 1.2146x; 1.0267x over previous
//
#include <hip/hip_runtime.h>
#include <cstdint>

// Fused butterfly-GLU-butterfly, round 6.
// Round-5 post-mortem: 2 blocks/CU doubled occupancy but only -8% time ->
// latency-bound on per-phase mats loads from L2 (805 MB/dispatch, each block
// reads all 384 matrices) with __syncthreads' vmcnt(0) drain killing any
// cross-phase overlap. This round: (a) rows=32/block (grid 512, verified
// round-4 nh indexing) -> mats L2 traffic halved, barriers/row halved;
// (b) raw s_barrier + manual lgkmcnt(0) (no vmcnt drain) + explicit prefetch
// of next phase's A-fragments across barriers (8-frag window);
// (c) L1A sa+sg merged into one 32-MFMA phase; (d) build_mats stores staged
// through LDS for coalesced dwordx4 writes. 1 block/CU (136KB LDS), 8 waves,
// VGPR budget 256 via __launch_bounds__(512,2).

typedef float          v4f __attribute__((ext_vector_type(4)));
typedef unsigned int   u4i __attribute__((ext_vector_type(4)));
typedef unsigned int   u2i __attribute__((ext_vector_type(2)));
typedef short          bf8 __attribute__((ext_vector_type(8)));  // 8 x bf16

#define MFMA16(A, B, C) __builtin_amdgcn_mfma_f32_16x16x32_bf16(A, B, C, 0, 0, 0)

// Raw workgroup barrier: guarantees LDS write visibility (lgkmcnt(0)) but
// leaves global loads (vmcnt) in flight across the barrier. Safe here: no
// mid-kernel global-memory communication between waves.
#define BAR() do {                                          \
    asm volatile("s_waitcnt lgkmcnt(0)" ::: "memory");      \
    __builtin_amdgcn_s_barrier();                           \
    asm volatile("" ::: "memory");                          \
} while (0)

__device__ __forceinline__ unsigned pk2(float a, float b) {
    unsigned ua = __float_as_uint(a) + 0x8000u;
    unsigned ub = __float_as_uint(b) + 0x8000u;
    return __builtin_amdgcn_perm(ub, ua, 0x07060302u);  // {b.hi16, a.hi16}
}

__device__ __forceinline__ v4f ub4(u2i u) {   // unpack 4 bf16 -> v4f
    v4f r;
    r.x = __uint_as_float(u.x << 16); r.y = __uint_as_float(u.x & 0xffff0000u);
    r.z = __uint_as_float(u.y << 16); r.w = __uint_as_float(u.y & 0xffff0000u);
    return r;
}

__device__ __forceinline__ float sigmf(float g) {
    return __builtin_amdgcn_rcpf(1.0f + __expf(-g));
}
__device__ __forceinline__ v4f sig4(v4f g) {
    v4f r; r.x = sigmf(g.x); r.y = sigmf(g.y); r.z = sigmf(g.z); r.w = sigmf(g.w);
    return r;
}

// byte offset into a [32 rows][1024 halfword] bf16 LDS tile, bank-swizzled
__device__ __forceinline__ int ab(int row, int hw) {
    return (row << 11) + (((hw) << 1) ^ ((row & 7) << 4));
}

// ---------------------------------------------------------------------------
// Pre-pass: 384 combined 32x32 bf16 matrices into d_ws (A-fragment order).
//   mid   0..127 : L1A [s][g]  stages 0..4 , p = 32g + r        (tw1)
//   mid 128..255 : L1B [s][l]  stages 5..9 , p = l + 32r        (tw1)
//   mid 256..319 : L2A [g2]    stages 0..4 , p = 32g2 + r       (tw2)
//   mid 320..383 : L2B [b][l2] stages 5..9 , p = l2+32r+1024b   (tw2),
//                  rows scaled by tw2[stage10][l2+32r][0][b]
// v3: LDS-staged output -> coalesced dwordx4 stores (was 32 scattered 2B/thr).
// ---------------------------------------------------------------------------
struct MP { const float* twf; int np, rbase, rstep, j0; };
__device__ __forceinline__ MP mparams(int mid, const float* tw1, const float* tw2) {
    MP p;
    if (mid < 128)      { p.twf = tw1 + (mid >> 5) * 20480;         p.np = 512;  p.rbase = (mid & 31) * 32; p.rstep = 1;  p.j0 = 0; }
    else if (mid < 256) { p.twf = tw1 + ((mid - 128) >> 5) * 20480; p.np = 512;  p.rbase = mid & 31;        p.rstep = 32; p.j0 = 5; }
    else if (mid < 320) { p.twf = tw2; p.np = 1024; p.rbase = (mid - 256) * 32; p.rstep = 1;  p.j0 = 0; }
    else                { p.twf = tw2; p.np = 1024;
                          p.rbase = (mid & 31) + (((mid - 320) >> 5) << 10);    p.rstep = 32; p.j0 = 5; }
    return p;
}

__global__ void build_mats(const float* __restrict__ tw1,
                           const float* __restrict__ tw2,
                           unsigned short* __restrict__ wsm)
{
    __shared__ v4f            tlds[160];   // 2 mids x 5 stages x 16 pairs
    __shared__ float          slds[64];    // 2 mids x 32 stage-10 row scales
    __shared__ unsigned short obuf[2048];  // 4KB output staging
    const int t = threadIdx.x;
    const int midb = blockIdx.x * 2;

    #pragma unroll
    for (int qq = 0; qq < 3; ++qq) {
        const int q = t + qq * 64;
        if (q < 160) {
            const int ml = (q >= 80) ? 1 : 0, rem = q - ml * 80;
            const int jj = rem >> 4, pr = rem & 15;
            const MP p = mparams(midb + ml, tw1, tw2);
            const int j  = p.j0 + jj;
            const int r0 = ((pr >> jj) << (jj + 1)) | (pr & ((1 << jj) - 1));
            const int pp = p.rbase + r0 * p.rstep;
            const int tidx = ((pp >> (j + 1)) << j) | (pp & ((1 << j) - 1));
            tlds[q] = *(const v4f*)(p.twf + (size_t)(j * p.np + tidx) * 4);
        }
    }
    {
        const int ml2 = t >> 5, r = t & 31, mid = midb + ml2;
        if (mid >= 320) {
            const int l2s = mid & 31, sb = (mid - 320) >> 5;
            slds[t] = tw2[(size_t)(10 * 1024 + l2s + 32 * r) * 4 + sb];
        }
    }
    __syncthreads();

    const int ml = t >> 5, c = t & 31, mid = midb + ml;
    float v[32];
    #pragma unroll
    for (int r = 0; r < 32; ++r) v[r] = (r == c) ? 1.0f : 0.0f;

    #pragma unroll
    for (int jj = 0; jj < 5; ++jj) {
        #pragma unroll
        for (int pr = 0; pr < 16; ++pr) {
            const int r0 = ((pr >> jj) << (jj + 1)) | (pr & ((1 << jj) - 1));
            const int r1 = r0 | (1 << jj);
            const v4f T  = tlds[ml * 80 + jj * 16 + pr];
            const float a = v[r0], b = v[r1];
            v[r0] = T.x * a + T.y * b;
            v[r1] = T.z * a + T.w * b;
        }
    }
    if (mid >= 320) {
        #pragma unroll
        for (int r = 0; r < 32; ++r) v[r] *= slds[ml * 32 + r];
    }
    #pragma unroll
    for (int r = 0; r < 32; ++r) {
        const int mt   = r >> 4;
        const int lane = (r & 15) + ((c >> 3) << 4);
        obuf[((ml * 2 + mt) * 64 + lane) * 8 + (c & 7)] =
            (unsigned short)((__float_as_uint(v[r]) + 0x8000u) >> 16);
    }
    __syncthreads();
    {
        const u4i* ob = (const u4i*)obuf;                 // 256 x 16B
        u4i* gb = (u4i*)(wsm + (size_t)midb * 1024);
        #pragma unroll
        for (int k = 0; k < 4; ++k) gb[t * 4 + k] = ob[t * 4 + k];
    }
}

// ---------------------------------------------------------------------------
// Main fused kernel. 512 blocks x 32 rows x 512 thr.
// LDS 136KB = actA(64K) + actB(64K) + b1t16(8K) -> 1 block/CU, 8 waves,
// VGPR budget 256. Raw barriers; mats prefetched across phase boundaries.
// Transposed-tile convention: value at position p stored at hw = 32*(p&31)+(p>>5).
// ---------------------------------------------------------------------------
__global__ __launch_bounds__(512, 2) void glu_bfly(
    const float* __restrict__ x, const float* __restrict__ b1,
    const float* __restrict__ b2, const bf8* __restrict__ mats,
    float* __restrict__ out)
{
    extern __shared__ char lds[];                 // 139264 B
    char*           actA  = lds;
    char*           actB  = lds + 65536;
    unsigned short* b1t16 = (unsigned short*)(lds + 131072);

    const int t = threadIdx.x, w = t >> 6, l = t & 63, lr = l & 15, lk = l >> 4;
    const int row0 = blockIdx.x * 32;
    const v4f vz = {0.f, 0.f, 0.f, 0.f};

    // ---- stage b1 (bf16) -> b1t16[(s<<10)+((r&31)<<5)+(r>>5)] -------------------
    {
        const v4f* bp = (const v4f*)(b1 + t * 8);
        const v4f a = bp[0], b = bp[1];
        const float vals[8] = {a.x, a.y, a.z, a.w, b.x, b.y, b.z, b.w};
        #pragma unroll
        for (int k = 0; k < 8; ++k) {
            const int gid = t * 8 + k, s = gid >> 10, r = gid & 1023;
            b1t16[(s << 10) + ((r & 31) << 5) + (r >> 5)] =
                (unsigned short)((__float_as_uint(vals[k]) + 0x8000u) >> 16);
        }
    }

    // ---- x B-fragments (32 rows via nh), reused by all four L1A applications ----
    bf8 xf[4][2];
    #pragma unroll
    for (int gi = 0; gi < 4; ++gi)
    #pragma unroll
    for (int nh = 0; nh < 2; ++nh) {
        const float* xp = x + (size_t)(row0 + nh * 16 + lr) * 1024 + (w * 4 + gi) * 32 + lk * 8;
        const v4f a = *(const v4f*)xp, b = *(const v4f*)(xp + 4);
        u4i uu; uu.x = pk2(a.x, a.y); uu.y = pk2(a.z, a.w);
        uu.z = pk2(b.x, b.y); uu.w = pk2(b.z, b.w);
        xf[gi][nh] = __builtin_bit_cast(bf8, uu);
    }

    unsigned z0p[4][2][2][2];   // half-0 L2B result, bf16-packed
    v4f fin[4][2][2];           // z0 + z1 (pre-bias)

    // prefetch PH1(h=0) sa-mats (crosses the b1/x staging into the first phase)
    bf8 m1a[8];
    #pragma unroll
    for (int q = 0; q < 8; ++q)
        m1a[q] = mats[((0 * 32 + w * 4 + (q >> 1)) * 2 + (q & 1)) * 64 + l];

    #pragma unroll
    for (int h = 0; h < 2; ++h) {
        const int sa = h, sg = h + 2;

        // ---- PH1 (merged): L1A sa -> actA, L1A sg -> actB (transposed) ----
        bf8 m1b[8];
        #pragma unroll
        for (int q = 0; q < 8; ++q)
            m1b[q] = mats[((sg * 32 + w * 4 + (q >> 1)) * 2 + (q & 1)) * 64 + l];
        {
            v4f acc[4][2][2];
            __builtin_amdgcn_s_setprio(1);
            #pragma unroll
            for (int gi = 0; gi < 4; ++gi)
            #pragma unroll
            for (int nh = 0; nh < 2; ++nh) {
                acc[gi][nh][0] = MFMA16(m1a[gi * 2 + 0], xf[gi][nh], vz);
                acc[gi][nh][1] = MFMA16(m1a[gi * 2 + 1], xf[gi][nh], vz);
            }
            __builtin_amdgcn_s_setprio(0);
            #pragma unroll
            for (int nh = 0; nh < 2; ++nh)
            #pragma unroll
            for (int mt = 0; mt < 2; ++mt)
            #pragma unroll
            for (int rg = 0; rg < 4; ++rg) {
                const int m = mt * 16 + lk * 4 + rg;
                u2i pv;
                pv.x = pk2(acc[0][nh][mt][rg], acc[1][nh][mt][rg]);
                pv.y = pk2(acc[2][nh][mt][rg], acc[3][nh][mt][rg]);
                *(u2i*)(actA + ab(nh * 16 + lr, 32 * m + 4 * w)) = pv;
            }
        }
        {
            v4f acc[4][2][2];
            __builtin_amdgcn_s_setprio(1);
            #pragma unroll
            for (int gi = 0; gi < 4; ++gi)
            #pragma unroll
            for (int nh = 0; nh < 2; ++nh) {
                acc[gi][nh][0] = MFMA16(m1b[gi * 2 + 0], xf[gi][nh], vz);
                acc[gi][nh][1] = MFMA16(m1b[gi * 2 + 1], xf[gi][nh], vz);
            }
            __builtin_amdgcn_s_setprio(0);
            #pragma unroll
            for (int nh = 0; nh < 2; ++nh)
            #pragma unroll
            for (int mt = 0; mt < 2; ++mt)
            #pragma unroll
            for (int rg = 0; rg < 4; ++rg) {
                const int m = mt * 16 + lk * 4 + rg;
                u2i pv;
                pv.x = pk2(acc[0][nh][mt][rg], acc[1][nh][mt][rg]);
                pv.y = pk2(acc[2][nh][mt][rg], acc[3][nh][mt][rg]);
                *(u2i*)(actB + ab(nh * 16 + lr, 32 * m + 4 * w)) = pv;
            }
        }
        // prefetch PH2 li=0 mats across the barrier
        bf8 cm[4];
        cm[0] = mats[((128 + sa * 32 + w * 4 + 0) * 2 + 0) * 64 + l];
        cm[1] = mats[((128 + sa * 32 + w * 4 + 0) * 2 + 1) * 64 + l];
        cm[2] = mats[((128 + sg * 32 + w * 4 + 0) * 2 + 0) * 64 + l];
        cm[3] = mats[((128 + sg * 32 + w * 4 + 0) * 2 + 1) * 64 + l];
        BAR();

        // ---- PH2: L1B(a) + L1B(g) + bias + GLU -> u (plain) into actA ----
        v4f uacc[4][2][2];
        #pragma unroll
        for (int li = 0; li < 4; ++li) {
            bf8 nm[4];
            if (li < 3) {   // rolling 1-ahead prefetch (in-phase)
                nm[0] = mats[((128 + sa * 32 + w * 4 + li + 1) * 2 + 0) * 64 + l];
                nm[1] = mats[((128 + sa * 32 + w * 4 + li + 1) * 2 + 1) * 64 + l];
                nm[2] = mats[((128 + sg * 32 + w * 4 + li + 1) * 2 + 0) * 64 + l];
                nm[3] = mats[((128 + sg * 32 + w * 4 + li + 1) * 2 + 1) * 64 + l];
            }
            const int lg = w * 4 + li;
            const bf8 fa0 = *(const bf8*)(actA + ab(lr,      32 * lg + 8 * lk));
            const bf8 fa1 = *(const bf8*)(actA + ab(16 + lr, 32 * lg + 8 * lk));
            const bf8 fg0 = *(const bf8*)(actB + ab(lr,      32 * lg + 8 * lk));
            const bf8 fg1 = *(const bf8*)(actB + ab(16 + lr, 32 * lg + 8 * lk));
            v4f ha[2][2], hg[2][2];
            __builtin_amdgcn_s_setprio(1);
            ha[0][0] = MFMA16(cm[0], fa0, vz); ha[0][1] = MFMA16(cm[1], fa0, vz);
            ha[1][0] = MFMA16(cm[0], fa1, vz); ha[1][1] = MFMA16(cm[1], fa1, vz);
            hg[0][0] = MFMA16(cm[2], fg0, vz); hg[0][1] = MFMA16(cm[3], fg0, vz);
            hg[1][0] = MFMA16(cm[2], fg1, vz); hg[1][1] = MFMA16(cm[3], fg1, vz);
            __builtin_amdgcn_s_setprio(0);
            const int bia = ((sa * 32 + lg) << 5) + lk * 4;
            const int big = ((sg * 32 + lg) << 5) + lk * 4;
            const v4f ba0 = ub4(*(const u2i*)&b1t16[bia]);
            const v4f ba1 = ub4(*(const u2i*)&b1t16[bia + 16]);
            const v4f bg0 = ub4(*(const u2i*)&b1t16[big]);
            const v4f bg1 = ub4(*(const u2i*)&b1t16[big + 16]);
            #pragma unroll
            for (int nh = 0; nh < 2; ++nh) {
                uacc[li][nh][0] = (ha[nh][0] + ba0) * sig4(hg[nh][0] + bg0);
                uacc[li][nh][1] = (ha[nh][1] + ba1) * sig4(hg[nh][1] + bg1);
            }
            if (li < 3) { cm[0] = nm[0]; cm[1] = nm[1]; cm[2] = nm[2]; cm[3] = nm[3]; }
        }
        // prefetch PH3 (L2A) mats; they stay in flight across BOTH barriers below
        bf8 m3[8];
        #pragma unroll
        for (int q = 0; q < 8; ++q)
            m3[q] = mats[((256 + 32 * h + w * 4 + (q >> 1)) * 2 + (q & 1)) * 64 + l];
        BAR();   // all reads of actA/actB complete
        #pragma unroll
        for (int nh = 0; nh < 2; ++nh)
        #pragma unroll
        for (int mt = 0; mt < 2; ++mt)
        #pragma unroll
        for (int rg = 0; rg < 4; ++rg) {
            const int m = mt * 16 + lk * 4 + rg;
            u2i pv;
            pv.x = pk2(uacc[0][nh][mt][rg], uacc[1][nh][mt][rg]);
            pv.y = pk2(uacc[2][nh][mt][rg], uacc[3][nh][mt][rg]);
            *(u2i*)(actA + ab(nh * 16 + lr, 32 * m + 4 * w)) = pv;  // plain: hw = p
        }
        BAR();

        // ---- PH3: L2A: u (actA, plain) -> zA (actB, transposed) ----
        {
            v4f acc[4][2][2];
            #pragma unroll
            for (int gi = 0; gi < 4; ++gi) {
                const int g = w * 4 + gi;
                #pragma unroll
                for (int nh = 0; nh < 2; ++nh) {
                    const bf8 f = *(const bf8*)(actA + ab(nh * 16 + lr, 32 * g + 8 * lk));
                    __builtin_amdgcn_s_setprio(1);
                    acc[gi][nh][0] = MFMA16(m3[gi * 2 + 0], f, vz);
                    acc[gi][nh][1] = MFMA16(m3[gi * 2 + 1], f, vz);
                    __builtin_amdgcn_s_setprio(0);
                }
            }
            // prefetch PH4 (L2B) mats across the barrier
            bf8 m4p[4];
            m4p[0] = mats[((320 + 32 * h + w * 4 + 0) * 2 + 0) * 64 + l];
            m4p[1] = mats[((320 + 32 * h + w * 4 + 0) * 2 + 1) * 64 + l];
            m4p[2] = mats[((320 + 32 * h + w * 4 + 1) * 2 + 0) * 64 + l];
            m4p[3] = mats[((320 + 32 * h + w * 4 + 1) * 2 + 1) * 64 + l];
            #pragma unroll
            for (int nh = 0; nh < 2; ++nh)
            #pragma unroll
            for (int mt = 0; mt < 2; ++mt)
            #pragma unroll
            for (int rg = 0; rg < 4; ++rg) {
                const int m = mt * 16 + lk * 4 + rg;
                u2i pv;
                pv.x = pk2(acc[0][nh][mt][rg], acc[1][nh][mt][rg]);
                pv.y = pk2(acc[2][nh][mt][rg], acc[3][nh][mt][rg]);
                *(u2i*)(actB + ab(nh * 16 + lr, 32 * m + 4 * w)) = pv;
            }
            BAR();

            // ---- PH4: L2B (stage-10 folded): result stays in registers ----
            bf8 m4[4];
            m4[0] = m4p[0]; m4[1] = m4p[1]; m4[2] = m4p[2]; m4[3] = m4p[3];
            #pragma unroll
            for (int li = 0; li < 4; ++li) {
                bf8 n4[2];
                if (li < 2) {   // rolling: li+2 mats
                    n4[0] = mats[((320 + 32 * h + w * 4 + li + 2) * 2 + 0) * 64 + l];
                    n4[1] = mats[((320 + 32 * h + w * 4 + li + 2) * 2 + 1) * 64 + l];
                }
                const int lg = w * 4 + li;
                const bf8 f0 = *(const bf8*)(actB + ab(lr,      32 * lg + 8 * lk));
                const bf8 f1 = *(const bf8*)(actB + ab(16 + lr, 32 * lg + 8 * lk));
                v4f zz[2][2];
                __builtin_amdgcn_s_setprio(1);
                zz[0][0] = MFMA16(m4[(li & 1) * 2 + 0], f0, vz);
                zz[0][1] = MFMA16(m4[(li & 1) * 2 + 1], f0, vz);
                zz[1][0] = MFMA16(m4[(li & 1) * 2 + 0], f1, vz);
                zz[1][1] = MFMA16(m4[(li & 1) * 2 + 1], f1, vz);
                __builtin_amdgcn_s_setprio(0);
                if (h == 0) {
                    #pragma unroll
                    for (int nh = 0; nh < 2; ++nh)
                    #pragma unroll
                    for (int mt = 0; mt < 2; ++mt) {
                        z0p[li][nh][mt][0] = pk2(zz[nh][mt].x, zz[nh][mt].y);
                        z0p[li][nh][mt][1] = pk2(zz[nh][mt].z, zz[nh][mt].w);
                    }
                } else {
                    #pragma unroll
                    for (int nh = 0; nh < 2; ++nh)
                    #pragma unroll
                    for (int mt = 0; mt < 2; ++mt) {
                        u2i uu; uu.x = z0p[li][nh][mt][0]; uu.y = z0p[li][nh][mt][1];
                        fin[li][nh][mt] = zz[nh][mt] + ub4(uu);
                    }
                }
                if (li < 2) { m4[(li & 1) * 2 + 0] = n4[0]; m4[(li & 1) * 2 + 1] = n4[1]; }
            }
        }
        if (h == 0) {   // prefetch PH1(h=1) sa-mats across the end-of-h barrier
            #pragma unroll
            for (int q = 0; q < 8; ++q)
                m1a[q] = mats[((1 * 32 + w * 4 + (q >> 1)) * 2 + (q & 1)) * 64 + l];
        }
        BAR();   // protects actA/actB WAR vs next-h PH1 writes (and epilogue staging)
    } // halves

    // ---- epilogue: stage fin (fp32) through lds[0,64K) for coalesced store ------
    #pragma unroll
    for (int nh = 0; nh < 2; ++nh) {
        #pragma unroll
        for (int mt = 0; mt < 2; ++mt)
        #pragma unroll
        for (int rg = 0; rg < 4; ++rg) {
            const int p0 = 4 * w + 32 * (mt * 16 + lk * 4 + rg);
            v4f vv;
            vv.x = fin[0][nh][mt][rg]; vv.y = fin[1][nh][mt][rg];
            vv.z = fin[2][nh][mt][rg]; vv.w = fin[3][nh][mt][rg];
            *(v4f*)(lds + (lr << 12) + ((p0 << 2) ^ ((lr & 7) << 4))) = vv;
        }
        BAR();
        {
            const int row = t >> 5, c0 = (t & 31) * 4;
            #pragma unroll
            for (int i = 0; i < 8; ++i) {
                const int col = c0 + 128 * i;
                v4f ov = *(const v4f*)(lds + (row << 12) + ((col << 2) ^ ((row & 7) << 4)));
                ov += *(const v4f*)(b2 + col);
                *(v4f*)(out + (size_t)(row0 + nh * 16 + row) * 1024 + col) = ov;
            }
        }
        BAR();
    }
}

extern "C" void kernel_launch(void* const* d_in, const int* in_sizes, int n_in,
                              void* d_out, int out_size, void* d_ws, size_t ws_size,
                              hipStream_t stream) {
    const float* x   = (const float*)d_in[0];
    const float* tw1 = (const float*)d_in[1];
    const float* b1  = (const float*)d_in[2];
    const float* tw2 = (const float*)d_in[3];
    const float* b2  = (const float*)d_in[4];

    build_mats<<<192, 64, 0, stream>>>(tw1, tw2, (unsigned short*)d_ws);

    (void)hipFuncSetAttribute((const void*)glu_bfly,
                              hipFuncAttributeMaxDynamicSharedMemorySize, 139264);
    glu_bfly<<<512, 512, 139264, stream>>>(x, b1, b2, (const bf8*)d_ws,
                                           (float*)d_out);
}